// Round 1
// baseline (725.105 us; speedup 1.0000x reference)
//
#include <hip/hip_runtime.h>

// FuncSelfAttention: B=2,S=256,E=64,H=W=32, CH=4, XH=YH=2 -> 16 heads, D=4096.
// 3 kernels: QKV-proj (MFMA), fused attention per (b,head,Qblock), out-proj (MFMA).

typedef _Float16 f16;
typedef _Float16 f16x8 __attribute__((ext_vector_type(8)));
typedef float f32x4 __attribute__((ext_vector_type(4)));

#define MFMA16(a, b, c) __builtin_amdgcn_mfma_f32_16x16x32_f16(a, b, c, 0, 0, 0)

// ---------------- K1: QKV projection ----------------
// Per (b,s): qkv[o=192][hw=1024] = sum_e wqkv[o][e] * seq[b,s,e,hw].
// Computed as C^T: M=hw (256-chunk), N=o(192), K=e(64).
// A = seq^T from LDS (transposed stage, XOR-swizzled e-octets), B = wqkv from global.
// grid 2048 = (b*s)*4, block 512 (8 waves, 4x2).
__global__ __launch_bounds__(512) void k_qkvproj(
    const float* __restrict__ seq, const float* __restrict__ wqkv,
    f16* __restrict__ Qb, f16* __restrict__ Kb, f16* __restrict__ Vb)
{
    __shared__ __align__(16) f16 Blds[256 * 72];   // [hw_l][e] row stride 72, e ^ ((row>>2&7)<<3)
    const int bid = blockIdx.x;
    const int bs = bid >> 2, cc = bid & 3;
    const int b = bs >> 8, s = bs & 255;
    const int tid = threadIdx.x;
    const float* sbase = seq + (size_t)bs * 65536 + cc * 256;

    // stage seq chunk [e=64][hw=256] -> Blds[hw][e] (transposed, swizzled)
    #pragma unroll
    for (int i = 0; i < 8; ++i) {
        int flat = tid + i * 512;
        int e = flat >> 6, n4 = flat & 63;
        float4 v = *(const float4*)(sbase + e * 1024 + n4 * 4);
        float vv[4] = {v.x, v.y, v.z, v.w};
        #pragma unroll
        for (int j = 0; j < 4; ++j) {
            int row = n4 * 4 + j;
            Blds[row * 72 + (e ^ (((row >> 2) & 7) << 3))] = (f16)vv[j];
        }
    }

    const int wid = tid >> 6, lane = tid & 63;
    const int l16 = lane & 15, lq = lane >> 4;
    const int wm = wid >> 1, wn = wid & 1;   // wave tile: m 64, n 96

    // B-operand frags from global wqkv (row o, 8 consecutive e)
    f16x8 wf[6][2];
    #pragma unroll
    for (int ni = 0; ni < 6; ++ni)
        #pragma unroll
        for (int ks = 0; ks < 2; ++ks) {
            const float* wp = wqkv + (wn * 96 + ni * 16 + l16) * 64 + ks * 32 + lq * 8;
            f16x8 t;
            #pragma unroll
            for (int j = 0; j < 8; ++j) t[j] = (f16)wp[j];
            wf[ni][ks] = t;
        }
    __syncthreads();

    f32x4 zz = {0.f, 0.f, 0.f, 0.f};
    f32x4 acc[4][6];
    #pragma unroll
    for (int mi = 0; mi < 4; ++mi)
        #pragma unroll
        for (int ni = 0; ni < 6; ++ni) acc[mi][ni] = zz;

    #pragma unroll
    for (int ks = 0; ks < 2; ++ks)
        #pragma unroll
        for (int mi = 0; mi < 4; ++mi) {
            int row = wm * 64 + mi * 16 + l16;
            f16x8 af = *(const f16x8*)&Blds[row * 72 + ((ks * 32 + lq * 8) ^ (((row >> 2) & 7) << 3))];
            #pragma unroll
            for (int ni = 0; ni < 6; ++ni)
                acc[mi][ni] = MFMA16(af, wf[ni][ks], acc[mi][ni]);
        }

    // scatter: o -> (split, ch, c), hw -> (Xi,xin,Yi,win); 4 in-lane rows = 4 consecutive win
    #pragma unroll
    for (int mi = 0; mi < 4; ++mi) {
        int hw = cc * 256 + wm * 64 + mi * 16 + lq * 4;
        int hfull = hw >> 5, wfull = hw & 31;
        int Xi = hfull >> 4, xin = hfull & 15, Yi = wfull >> 4, win = wfull & 15;
        int sh = Xi * 2 + Yi;
        #pragma unroll
        for (int ni = 0; ni < 6; ++ni) {
            int o = wn * 96 + ni * 16 + l16;
            int split = o >> 6, e = o & 63, ch = e >> 4, c = e & 15;
            f16* dst = (split == 0) ? Qb : (split == 1) ? Kb : Vb;
            int head = sh * 4 + ch;
            int d = c * 256 + xin * 16 + win;
            f16 t4[4];
            #pragma unroll
            for (int r = 0; r < 4; ++r) t4[r] = (f16)acc[mi][ni][r];
            *(uint2*)(dst + ((size_t)(b * 16 + head) * 256 + s) * 4096 + d) = *(uint2*)t4;
        }
    }
}

// ---------------- K2: fused attention ----------------
// One wg per (b*head, qblock of 32 rows). 512 threads, 8 waves.
// Phase1: scores = Q K^T (K=4096 in 64-chunks through LDS). Phase2: fp32 softmax.
// Phase3: PV with V transposed on the fly in LDS (swizzled).
// SA output aliases the Q buffer (wg writes exactly its own Q rows).
__global__ __launch_bounds__(512) void k_attn(
    const f16* __restrict__ Q, const f16* __restrict__ K,
    const f16* __restrict__ V, f16* __restrict__ SA)
{
    __shared__ __align__(16) char lds[50304];
    f16* Plds  = (f16*)lds;                    // [32][264] fp16 (after phase1)
    float* rsum = (float*)(lds + 16896);       // [32]
    float* Sld  = (float*)(lds + 17024);       // [32][260] fp32 (after phase1, dead after softmax)
    f16* Kc    = (f16*)lds;                    // [256][72] (phase1)
    f16* Qc    = (f16*)(lds + 36864);          // [32][72]  (phase1)
    f16* Vtl   = (f16*)(lds + 17024);          // [256 t][64 d] swizzled (phase3)

    const int bid = blockIdx.x, bh = bid >> 3, qb = bid & 7;
    const int tid = threadIdx.x, wid = tid >> 6, lane = tid & 63;
    const int l16 = lane & 15, lq = lane >> 4;
    const f16* Qbase = Q + ((size_t)bh * 256 + qb * 32) * 4096;
    const f16* Kbase = K + (size_t)bh * 256 * 4096;

    const int wm = wid >> 2, wn = wid & 3;     // phase1 wave: rows wm*16, cols wn*64

    f32x4 zz = {0.f, 0.f, 0.f, 0.f};
    f32x4 acc[4];
    #pragma unroll
    for (int i = 0; i < 4; ++i) acc[i] = zz;

    for (int dc = 0; dc < 64; ++dc) {
        __syncthreads();
        for (int flat = tid; flat < 2304; flat += 512) {
            if (flat < 256) {
                int r = flat >> 3, o8 = flat & 7;
                *(uint4*)&Qc[r * 72 + o8 * 8] = *(const uint4*)(Qbase + (size_t)r * 4096 + dc * 64 + o8 * 8);
            } else {
                int f2 = flat - 256, r = f2 >> 3, o8 = f2 & 7;
                *(uint4*)&Kc[r * 72 + o8 * 8] = *(const uint4*)(Kbase + (size_t)r * 4096 + dc * 64 + o8 * 8);
            }
        }
        __syncthreads();
        #pragma unroll
        for (int ks = 0; ks < 2; ++ks) {
            f16x8 af = *(const f16x8*)&Qc[(wm * 16 + l16) * 72 + ks * 32 + lq * 8];
            #pragma unroll
            for (int ni = 0; ni < 4; ++ni) {
                f16x8 bf = *(const f16x8*)&Kc[(wn * 64 + ni * 16 + l16) * 72 + ks * 32 + lq * 8];
                acc[ni] = MFMA16(af, bf, acc[ni]);
            }
        }
    }
    __syncthreads();
    const float scale = 0.015625f;  // 1/sqrt(16*16*16)
    #pragma unroll
    for (int ni = 0; ni < 4; ++ni)
        #pragma unroll
        for (int r = 0; r < 4; ++r)
            Sld[(wm * 16 + lq * 4 + r) * 260 + wn * 64 + ni * 16 + l16] = acc[ni][r] * scale;
    __syncthreads();

    // softmax: 16 threads per row, 16 cols each; P kept unnormalized, 1/sum applied in PV epilogue
    {
        int row = tid >> 4, sub = tid & 15;
        const float* sp = Sld + row * 260 + sub * 16;
        float vals[16], mx = -1e30f;
        #pragma unroll
        for (int j = 0; j < 16; ++j) { vals[j] = sp[j]; mx = fmaxf(mx, vals[j]); }
        #pragma unroll
        for (int m = 1; m < 16; m <<= 1) mx = fmaxf(mx, __shfl_xor(mx, m));
        float sum = 0.f;
        #pragma unroll
        for (int j = 0; j < 16; ++j) { float e = __expf(vals[j] - mx); vals[j] = e; sum += e; }
        #pragma unroll
        for (int m = 1; m < 16; m <<= 1) sum += __shfl_xor(sum, m);
        if (sub == 0) rsum[row] = 1.f / sum;
        f16 pv[16];
        #pragma unroll
        for (int j = 0; j < 16; ++j) pv[j] = (f16)vals[j];
        *(uint4*)&Plds[row * 264 + sub * 16]     = ((uint4*)pv)[0];
        *(uint4*)&Plds[row * 264 + sub * 16 + 8] = ((uint4*)pv)[1];
    }
    __syncthreads();

    // PV: per 64-wide d chunk, stage V[256 t][64 d] swizzled; B-frag = 8-gather along t
    const f16* Vbase = V + (size_t)bh * 256 * 4096;
    f16* SAb = SA + ((size_t)bh * 256 + qb * 32) * 4096;
    for (int dc = 0; dc < 64; ++dc) {
        __syncthreads();
        for (int flat = tid; flat < 2048; flat += 512) {
            int tl = flat >> 3, d8 = flat & 7;
            uint4 v = *(const uint4*)(Vbase + (size_t)tl * 4096 + dc * 64 + d8 * 8);
            int o8 = d8 ^ ((tl ^ (tl >> 3)) & 7);
            *(uint4*)&Vtl[tl * 64 + o8 * 8] = v;
        }
        __syncthreads();
        f32x4 pacc = zz;
        #pragma unroll
        for (int kt = 0; kt < 8; ++kt) {
            f16x8 af = *(const f16x8*)&Plds[(wm * 16 + l16) * 264 + kt * 32 + lq * 8];
            int dd = wn * 16 + l16;
            f16 bt[8];
            #pragma unroll
            for (int j = 0; j < 8; ++j) {
                int tt = kt * 32 + lq * 8 + j;
                int oct = (dd >> 3) ^ ((tt ^ (tt >> 3)) & 7);
                bt[j] = Vtl[tt * 64 + oct * 8 + (dd & 7)];
            }
            f16x8 bf = *(const f16x8*)bt;
            pacc = MFMA16(af, bf, pacc);
        }
        #pragma unroll
        for (int r = 0; r < 4; ++r) {
            int srow = wm * 16 + lq * 4 + r;
            SAb[(size_t)srow * 4096 + dc * 64 + wn * 16 + l16] = (f16)(pacc[r] * rsum[srow]);
        }
    }
}

// ---------------- K3: output projection ----------------
// Per (b,s,hw-chunk 256): out[e][hw] = wout[e][e'] * sa[e'][hw] + bout[e].
// SA gathered into LDS [e'][256 hw] with octet XOR swizzle; A=wout from global.
// grid 2048, block 256 (4 waves, each n=64).
__global__ __launch_bounds__(256) void k_outproj(
    const f16* __restrict__ SA, const float* __restrict__ wout,
    const float* __restrict__ bout, float* __restrict__ out)
{
    __shared__ __align__(16) f16 Sl[64 * 256];  // [e'][hw], octet ^ ((e'^(e'>>3))&7)
    const int bid = blockIdx.x, bs = bid >> 2, cc = bid & 3;
    const int b = bs >> 8, s = bs & 255;
    const int tid = threadIdx.x, wid = tid >> 6, lane = tid & 63;
    const int l16 = lane & 15, lq = lane >> 4;
    const int Xi = cc >> 1, xb = (cc & 1) * 8;

    #pragma unroll
    for (int i = 0; i < 8; ++i) {
        int flat = tid + i * 256;  // bits: [ch2][Yi1][c4][xin3][win8 1]
        int win8 = flat & 1, xin = (flat >> 1) & 7, c = (flat >> 4) & 15;
        int Yi = (flat >> 8) & 1, ch = flat >> 9;
        int head = (Xi * 2 + Yi) * 4 + ch;
        int d = c * 256 + (xb + xin) * 16 + win8 * 8;
        uint4 v = *(const uint4*)(SA + ((size_t)(b * 16 + head) * 256 + s) * 4096 + d);
        int ep = ch * 16 + c;
        int hwl = xin * 32 + Yi * 16 + win8 * 8;
        int f = (ep ^ (ep >> 3)) & 7;
        *(uint4*)&Sl[ep * 256 + (((hwl >> 3) ^ f) << 3)] = v;
    }

    f16x8 afr[4][2];
    #pragma unroll
    for (int mi = 0; mi < 4; ++mi)
        #pragma unroll
        for (int ks = 0; ks < 2; ++ks) {
            const float* wp = wout + (mi * 16 + l16) * 64 + ks * 32 + lq * 8;
            f16x8 t;
            #pragma unroll
            for (int j = 0; j < 8; ++j) t[j] = (f16)wp[j];
            afr[mi][ks] = t;
        }
    __syncthreads();

    f32x4 zz = {0.f, 0.f, 0.f, 0.f};
    f32x4 acc[4][4];
    #pragma unroll
    for (int mi = 0; mi < 4; ++mi)
        #pragma unroll
        for (int ni = 0; ni < 4; ++ni) acc[mi][ni] = zz;

    #pragma unroll
    for (int ks = 0; ks < 2; ++ks)
        #pragma unroll
        for (int ni = 0; ni < 4; ++ni) {
            int n = wid * 64 + ni * 16 + l16;
            f16 bt[8];
            #pragma unroll
            for (int j = 0; j < 8; ++j) {
                int e2 = ks * 32 + lq * 8 + j;
                int f2 = (e2 ^ (e2 >> 3)) & 7;
                bt[j] = Sl[e2 * 256 + ((((n >> 3) ^ f2) << 3) | (n & 7))];
            }
            f16x8 bf = *(const f16x8*)bt;
            #pragma unroll
            for (int mi = 0; mi < 4; ++mi)
                acc[mi][ni] = MFMA16(afr[mi][ks], bf, acc[mi][ni]);
        }

    float* obase = out + (size_t)bs * 65536 + cc * 256;
    #pragma unroll
    for (int mi = 0; mi < 4; ++mi)
        #pragma unroll
        for (int r = 0; r < 4; ++r) {
            int e = mi * 16 + lq * 4 + r;
            float bias = bout[e];
            #pragma unroll
            for (int ni = 0; ni < 4; ++ni) {
                int n = wid * 64 + ni * 16 + l16;
                obase[(size_t)e * 1024 + n] = acc[mi][ni][r] + bias;
            }
        }
}

extern "C" void kernel_launch(void* const* d_in, const int* in_sizes, int n_in,
                              void* d_out, int out_size, void* d_ws, size_t ws_size,
                              hipStream_t stream)
{
    const float* seq  = (const float*)d_in[0];
    const float* wqkv = (const float*)d_in[1];
    const float* wout = (const float*)d_in[2];
    const float* bout = (const float*)d_in[3];
    float* out = (float*)d_out;

    const size_t NB = (size_t)2 * 16 * 256 * 4096;  // 33,554,432 f16 per buffer
    f16* Qb = (f16*)d_ws;       // also reused as SA (each attn wg overwrites only its own Q rows)
    f16* Kb = Qb + NB;
    f16* Vb = Kb + NB;
    // total ws use: 3 * 64 MiB = 201,326,592 bytes

    hipLaunchKernelGGL(k_qkvproj, dim3(2048), dim3(512), 0, stream, seq, wqkv, Qb, Kb, Vb);
    hipLaunchKernelGGL(k_attn,    dim3(256),  dim3(512), 0, stream, Qb, Kb, Vb, Qb);
    hipLaunchKernelGGL(k_outproj, dim3(2048), dim3(256), 0, stream, Qb, wout, bout, out);
}